// Round 5
// baseline (158.232 us; speedup 1.0000x reference)
//
#include <hip/hip_runtime.h>
#include <math.h>

// SDE Euler-Maruyama path generator — affine-scan decomposition, v4.
//   step:  x' = S_k x + t_k,  S_k = I + dt*A + diag(dW_k)*C,  t_k = dt*b + dW_k*d
// Phase 1: per (path, chunk) compose L=50 step-affines -> (M, v)     [B*NC threads]
// Phase 2: per path, serial scan over NC=50 chunk affines; overwrites each
//          transform slot's first float4 with the chunk-start state.
// Phase 3: replay with LDS transpose for contiguous stores; output stores are
//          NON-TEMPORAL (no write-allocate -> no RFO fetch serialization),
//          noise re-reads are non-temporal loads (hit L3, don't re-cache).

constexpr int B_N  = 4096;
constexpr int T_N  = 2500;
constexpr int L    = 50;            // steps per chunk
constexpr int NC   = T_N / L;       // 50 chunks
constexpr int FL   = 10;            // steps per flush/prefetch sub-chunk
constexpr int NFL  = L / FL;        // 5
constexpr int ROWF = (T_N + 1) * 3; // floats per output path row

// d_ws layout (floats): trans [NC][B][12]  (M 9, v 3; slot[0:4] later
// overwritten by scan with the chunk-start state)  -> 9.83 MB
__global__ __launch_bounds__(64)
void sde_chunk_transforms(const float* __restrict__ A,
                          const float* __restrict__ bv,
                          const float* __restrict__ C,
                          const float* __restrict__ dv,
                          const float* __restrict__ noise,
                          float* __restrict__ trans)
{
    const int b = blockIdx.x * 64 + threadIdx.x;
    const int c = blockIdx.y;

    const float dt  = 0.002f;
    const float sdt = sqrtf(dt);

    float IA[3][3], Cs[3][3], bdt[3], ds[3];
#pragma unroll
    for (int i = 0; i < 3; ++i) {
        bdt[i] = bv[i] * dt;
        ds[i]  = dv[i] * sdt;
#pragma unroll
        for (int j = 0; j < 3; ++j) {
            IA[i][j] = A[i * 3 + j] * dt + (i == j ? 1.0f : 0.0f);
            Cs[i][j] = C[i * 3 + j] * sdt;
        }
    }

    float M[3][3] = {{1,0,0},{0,1,0},{0,0,1}};
    float v[3] = {0, 0, 0};

    const float* __restrict__ nb = noise + (size_t)c * L * (B_N * 3) + (size_t)b * 3;
    const size_t nstride = (size_t)B_N * 3;

    float bufA[FL][3], bufB[FL][3];

    auto loadChunk = [&](float (&buf)[FL][3], int s) {
#pragma unroll
        for (int k = 0; k < FL; ++k) {
            const float* p = nb + ((size_t)s * FL + k) * nstride;
            buf[k][0] = p[0];
            buf[k][1] = p[1];
            buf[k][2] = p[2];
        }
    };

    auto compChunk = [&](const float (&buf)[FL][3]) {
#pragma unroll
        for (int k = 0; k < FL; ++k) {
            const float e[3] = { buf[k][0], buf[k][1], buf[k][2] };
            float S[3][3], t[3];
#pragma unroll
            for (int i = 0; i < 3; ++i) {
                t[i] = fmaf(e[i], ds[i], bdt[i]);
#pragma unroll
                for (int j = 0; j < 3; ++j)
                    S[i][j] = fmaf(e[i], Cs[i][j], IA[i][j]);
            }
            float nM[3][3], nv[3];
#pragma unroll
            for (int i = 0; i < 3; ++i) {
#pragma unroll
                for (int j = 0; j < 3; ++j)
                    nM[i][j] = fmaf(S[i][2], M[2][j], fmaf(S[i][1], M[1][j], S[i][0] * M[0][j]));
                nv[i] = fmaf(S[i][2], v[2], fmaf(S[i][1], v[1], S[i][0] * v[0])) + t[i];
            }
#pragma unroll
            for (int i = 0; i < 3; ++i) {
                v[i] = nv[i];
#pragma unroll
                for (int j = 0; j < 3; ++j) M[i][j] = nM[i][j];
            }
        }
    };

    loadChunk(bufA, 0);
    for (int s = 0; s < NFL; s += 2) {
        if (s + 1 < NFL) loadChunk(bufB, s + 1);
        compChunk(bufA);
        if (s + 2 < NFL) loadChunk(bufA, s + 2);
        if (s + 1 < NFL) compChunk(bufB);
    }

    float* tp = trans + ((size_t)c * B_N + b) * 12;
    float4 w0 = { M[0][0], M[0][1], M[0][2], M[1][0] };
    float4 w1 = { M[1][1], M[1][2], M[2][0], M[2][1] };
    float4 w2 = { M[2][2], v[0],    v[1],    v[2]    };
    ((float4*)tp)[0] = w0;
    ((float4*)tp)[1] = w1;
    ((float4*)tp)[2] = w2;
}

__global__ __launch_bounds__(64)
void sde_scan(const float* __restrict__ x0,
              float* __restrict__ trans,
              float* __restrict__ out)
{
    const int b = blockIdx.x * 64 + threadIdx.x;

    float x[3] = { x0[b * 3 + 0], x0[b * 3 + 1], x0[b * 3 + 2] };

    float* op = out + (size_t)b * ROWF;
    op[0] = x[0]; op[1] = x[1]; op[2] = x[2];

    float4* tp0 = (float4*)(trans + (size_t)b * 12);
    const size_t cstride4 = (size_t)B_N * 3;   // float4 stride between chunks

    float4 a0 = tp0[0], a1 = tp0[1], a2 = tp0[2];

    for (int c = 0; c < NC; ++c) {
        float4 b0, b1, b2;
        if (c + 1 < NC) {
            const float4* tn = tp0 + (size_t)(c + 1) * cstride4;
            b0 = tn[0]; b1 = tn[1]; b2 = tn[2];
        }

        // overwrite slot[0:4] (already consumed into a0..a2) with chunk-start state
        tp0[(size_t)c * cstride4] = make_float4(x[0], x[1], x[2], 0.0f);

        const float n0 = fmaf(a0.x, x[0], fmaf(a0.y, x[1], fmaf(a0.z, x[2], a2.y)));
        const float n1 = fmaf(a0.w, x[0], fmaf(a1.x, x[1], fmaf(a1.y, x[2], a2.z)));
        const float n2 = fmaf(a1.z, x[0], fmaf(a1.w, x[1], fmaf(a2.x, x[2], a2.w)));
        x[0] = n0; x[1] = n1; x[2] = n2;

        a0 = b0; a1 = b1; a2 = b2;
    }
}

__global__ __launch_bounds__(64)
void sde_replay(const float* __restrict__ A,
                const float* __restrict__ bv,
                const float* __restrict__ C,
                const float* __restrict__ dv,
                const float* __restrict__ noise,
                const float* __restrict__ trans,
                float* __restrict__ out)
{
    __shared__ float tile[64][31];   // wave-private (1 wave/block); stride 31 -> 2-way max (free)

    const int lane = threadIdx.x & 63;
    const int pg   = blockIdx.x & 63;   // path group
    const int c    = blockIdx.x >> 6;   // chunk 0..49
    const int b    = (pg << 6) | lane;

    const float dt  = 0.002f;
    const float sdt = sqrtf(dt);

    float Adt[3][3], Cs[3][3], bdt[3], dsv[3];
#pragma unroll
    for (int i = 0; i < 3; ++i) {
        bdt[i] = bv[i] * dt;
        dsv[i] = dv[i] * sdt;
#pragma unroll
        for (int j = 0; j < 3; ++j) {
            Adt[i][j] = A[i * 3 + j] * dt;
            Cs[i][j]  = C[i * 3 + j] * sdt;
        }
    }

    const float4 xb = *(const float4*)(trans + ((size_t)c * B_N + b) * 12);
    float x0r = xb.x, x1r = xb.y, x2r = xb.z;

    const float* __restrict__ nb = noise + (size_t)c * L * (B_N * 3) + (size_t)b * 3;
    const size_t nstride = (size_t)B_N * 3;

    // store roles: instr i writes paths {2i, 2i+1}; lanes 0-29 / 32-61 cover
    // 30 consecutive floats (120 B) of one path per instruction.
    const int  half = lane >> 5;              // 0 or 1
    const int  r    = lane & 31;              // 0..31
    const bool act  = r < 30;
    float* __restrict__ sb = out + (size_t)((pg << 6) + half) * ROWF
                                 + (size_t)(c * L + 1) * 3 + r;

    float bufA[FL][3], bufB[FL][3];

    auto loadChunk = [&](float (&buf)[FL][3], int s) {
#pragma unroll
        for (int k = 0; k < FL; ++k) {
            const float* p = nb + ((size_t)s * FL + k) * nstride;
            buf[k][0] = __builtin_nontemporal_load(p + 0);
            buf[k][1] = __builtin_nontemporal_load(p + 1);
            buf[k][2] = __builtin_nontemporal_load(p + 2);
        }
    };

    auto doFlush = [&](const float (&buf)[FL][3], int fl) {
        float st[FL][3];
#pragma unroll
        for (int k = 0; k < FL; ++k) {
            const float e0 = buf[k][0], e1 = buf[k][1], e2 = buf[k][2];

            const float a0 = fmaf(Adt[0][2], x2r, fmaf(Adt[0][1], x1r, fmaf(Adt[0][0], x0r, bdt[0])));
            const float a1 = fmaf(Adt[1][2], x2r, fmaf(Adt[1][1], x1r, fmaf(Adt[1][0], x0r, bdt[1])));
            const float a2 = fmaf(Adt[2][2], x2r, fmaf(Adt[2][1], x1r, fmaf(Adt[2][0], x0r, bdt[2])));

            const float c0 = fmaf(Cs[0][2], x2r, fmaf(Cs[0][1], x1r, fmaf(Cs[0][0], x0r, dsv[0])));
            const float c1 = fmaf(Cs[1][2], x2r, fmaf(Cs[1][1], x1r, fmaf(Cs[1][0], x0r, dsv[1])));
            const float c2 = fmaf(Cs[2][2], x2r, fmaf(Cs[2][1], x1r, fmaf(Cs[2][0], x0r, dsv[2])));

            const float n0 = fmaf(c0, e0, x0r + a0);
            const float n1 = fmaf(c1, e1, x1r + a1);
            const float n2 = fmaf(c2, e2, x2r + a2);

            st[k][0] = n0; st[k][1] = n1; st[k][2] = n2;
            x0r = n0; x1r = n1; x2r = n2;
        }

        // WAR: previous flush's cross-lane LDS reads must be complete
        asm volatile("s_waitcnt lgkmcnt(0)" ::: "memory");

#pragma unroll
        for (int k = 0; k < FL; ++k) {
            tile[lane][k * 3 + 0] = st[k][0];
            tile[lane][k * 3 + 1] = st[k][1];
            tile[lane][k * 3 + 2] = st[k][2];
        }

        // RAW: writes visible before cross-lane reads
        asm volatile("s_waitcnt lgkmcnt(0)" ::: "memory");
        __builtin_amdgcn_sched_barrier(0);

        if (act) {
#pragma unroll
            for (int i = 0; i < 32; ++i) {
                const float val = tile[2 * i + half][r];
                __builtin_nontemporal_store(val, sb + (size_t)(2 * i) * ROWF + fl * (FL * 3));
            }
        }
    };

    loadChunk(bufA, 0);
    loadChunk(bufB, 1);
    doFlush(bufA, 0);
    loadChunk(bufA, 2);
    doFlush(bufB, 1);
    loadChunk(bufB, 3);
    doFlush(bufA, 2);
    loadChunk(bufA, 4);
    doFlush(bufB, 3);
    doFlush(bufA, 4);
}

extern "C" void kernel_launch(void* const* d_in, const int* in_sizes, int n_in,
                              void* d_out, int out_size, void* d_ws, size_t ws_size,
                              hipStream_t stream) {
    const float* x0    = (const float*)d_in[0];
    const float* A     = (const float*)d_in[1];
    const float* bv    = (const float*)d_in[2];
    const float* C     = (const float*)d_in[3];
    const float* dv    = (const float*)d_in[4];
    const float* noise = (const float*)d_in[5];
    float* out = (float*)d_out;

    float* trans = (float*)d_ws;   // 9.83 MB

    dim3 gridPC(B_N / 64, NC);

    sde_chunk_transforms<<<gridPC, 64, 0, stream>>>(A, bv, C, dv, noise, trans);
    sde_scan<<<B_N / 64, 64, 0, stream>>>(x0, trans, out);
    sde_replay<<<64 * NC, 64, 0, stream>>>(A, bv, C, dv, noise, trans, out);
}

// Round 6
// 103.443 us; speedup vs baseline: 1.5297x; 1.5297x over previous
//
#include <hip/hip_runtime.h>
#include <math.h>

// SDE Euler-Maruyama path generator — affine-scan decomposition, v5.
//   step:  x' = S_k x + t_k,  S_k = I + dt*A + diag(dW_k)*C,  t_k = dt*b + dW_k*d
// Phase 1: per (path, chunk) compose L=50 step-affines -> (M, v)     [B*NC threads]
// Phase 2: per path, serial scan over NC=50 chunk affines; overwrites each
//          transform slot's first float4 with the chunk-start state.
// Phase 3: replay (round-3 structure: 256-thread blocks, LDS transpose,
//          NORMAL stores so L2 write-combines partial lines) with
//          TRIPLE-BUFFERED noise prefetch (depth 2) to cover L3/HBM latency.

constexpr int B_N  = 4096;
constexpr int T_N  = 2500;
constexpr int L    = 50;            // steps per chunk
constexpr int NC   = T_N / L;       // 50 chunks
constexpr int FL   = 10;            // steps per flush/prefetch sub-chunk
constexpr int NFL  = L / FL;        // 5
constexpr int ROWF = (T_N + 1) * 3; // floats per output path row

// d_ws layout (floats): trans [NC][B][12]  (M 9, v 3; slot[0:4] later
// overwritten by scan with the chunk-start state)  -> 9.83 MB
__global__ __launch_bounds__(64)
void sde_chunk_transforms(const float* __restrict__ A,
                          const float* __restrict__ bv,
                          const float* __restrict__ C,
                          const float* __restrict__ dv,
                          const float* __restrict__ noise,
                          float* __restrict__ trans)
{
    const int b = blockIdx.x * 64 + threadIdx.x;
    const int c = blockIdx.y;

    const float dt  = 0.002f;
    const float sdt = sqrtf(dt);

    float IA[3][3], Cs[3][3], bdt[3], ds[3];
#pragma unroll
    for (int i = 0; i < 3; ++i) {
        bdt[i] = bv[i] * dt;
        ds[i]  = dv[i] * sdt;
#pragma unroll
        for (int j = 0; j < 3; ++j) {
            IA[i][j] = A[i * 3 + j] * dt + (i == j ? 1.0f : 0.0f);
            Cs[i][j] = C[i * 3 + j] * sdt;
        }
    }

    float M[3][3] = {{1,0,0},{0,1,0},{0,0,1}};
    float v[3] = {0, 0, 0};

    const float* __restrict__ nb = noise + (size_t)c * L * (B_N * 3) + (size_t)b * 3;
    const size_t nstride = (size_t)B_N * 3;

    float bufA[FL][3], bufB[FL][3];

    auto loadChunk = [&](float (&buf)[FL][3], int s) {
#pragma unroll
        for (int k = 0; k < FL; ++k) {
            const float* p = nb + ((size_t)s * FL + k) * nstride;
            buf[k][0] = p[0];
            buf[k][1] = p[1];
            buf[k][2] = p[2];
        }
    };

    auto compChunk = [&](const float (&buf)[FL][3]) {
#pragma unroll
        for (int k = 0; k < FL; ++k) {
            const float e[3] = { buf[k][0], buf[k][1], buf[k][2] };
            float S[3][3], t[3];
#pragma unroll
            for (int i = 0; i < 3; ++i) {
                t[i] = fmaf(e[i], ds[i], bdt[i]);
#pragma unroll
                for (int j = 0; j < 3; ++j)
                    S[i][j] = fmaf(e[i], Cs[i][j], IA[i][j]);
            }
            float nM[3][3], nv[3];
#pragma unroll
            for (int i = 0; i < 3; ++i) {
#pragma unroll
                for (int j = 0; j < 3; ++j)
                    nM[i][j] = fmaf(S[i][2], M[2][j], fmaf(S[i][1], M[1][j], S[i][0] * M[0][j]));
                nv[i] = fmaf(S[i][2], v[2], fmaf(S[i][1], v[1], S[i][0] * v[0])) + t[i];
            }
#pragma unroll
            for (int i = 0; i < 3; ++i) {
                v[i] = nv[i];
#pragma unroll
                for (int j = 0; j < 3; ++j) M[i][j] = nM[i][j];
            }
        }
    };

    loadChunk(bufA, 0);
    for (int s = 0; s < NFL; s += 2) {
        if (s + 1 < NFL) loadChunk(bufB, s + 1);
        compChunk(bufA);
        if (s + 2 < NFL) loadChunk(bufA, s + 2);
        if (s + 1 < NFL) compChunk(bufB);
    }

    float* tp = trans + ((size_t)c * B_N + b) * 12;
    float4 w0 = { M[0][0], M[0][1], M[0][2], M[1][0] };
    float4 w1 = { M[1][1], M[1][2], M[2][0], M[2][1] };
    float4 w2 = { M[2][2], v[0],    v[1],    v[2]    };
    ((float4*)tp)[0] = w0;
    ((float4*)tp)[1] = w1;
    ((float4*)tp)[2] = w2;
}

__global__ __launch_bounds__(64)
void sde_scan(const float* __restrict__ x0,
              float* __restrict__ trans,
              float* __restrict__ out)
{
    const int b = blockIdx.x * 64 + threadIdx.x;

    float x[3] = { x0[b * 3 + 0], x0[b * 3 + 1], x0[b * 3 + 2] };

    float* op = out + (size_t)b * ROWF;
    op[0] = x[0]; op[1] = x[1]; op[2] = x[2];

    float4* tp0 = (float4*)(trans + (size_t)b * 12);
    const size_t cstride4 = (size_t)B_N * 3;   // float4 stride between chunks

    float4 a0 = tp0[0], a1 = tp0[1], a2 = tp0[2];

    for (int c = 0; c < NC; ++c) {
        float4 b0, b1, b2;
        if (c + 1 < NC) {
            const float4* tn = tp0 + (size_t)(c + 1) * cstride4;
            b0 = tn[0]; b1 = tn[1]; b2 = tn[2];
        }

        // overwrite slot[0:4] (already consumed into a0..a2) with chunk-start state
        tp0[(size_t)c * cstride4] = make_float4(x[0], x[1], x[2], 0.0f);

        const float n0 = fmaf(a0.x, x[0], fmaf(a0.y, x[1], fmaf(a0.z, x[2], a2.y)));
        const float n1 = fmaf(a0.w, x[0], fmaf(a1.x, x[1], fmaf(a1.y, x[2], a2.z)));
        const float n2 = fmaf(a1.z, x[0], fmaf(a1.w, x[1], fmaf(a2.x, x[2], a2.w)));
        x[0] = n0; x[1] = n1; x[2] = n2;

        a0 = b0; a1 = b1; a2 = b2;
    }
}

__global__ __launch_bounds__(256)
void sde_replay(const float* __restrict__ A,
                const float* __restrict__ bv,
                const float* __restrict__ C,
                const float* __restrict__ dv,
                const float* __restrict__ noise,
                const float* __restrict__ trans,
                float* __restrict__ out)
{
    __shared__ float lds[4][64][31];   // wave-private tiles; stride 31 -> 2-way max (free)

    const int widx = threadIdx.x >> 6;
    const int lane = threadIdx.x & 63;
    const int wg   = blockIdx.x * 4 + widx;   // 0..3199
    const int pg   = wg & 63;                 // path group
    const int c    = wg >> 6;                 // chunk 0..49
    const int b    = (pg << 6) | lane;

    const float dt  = 0.002f;
    const float sdt = sqrtf(dt);

    float Adt[3][3], Cs[3][3], bdt[3], dsv[3];
#pragma unroll
    for (int i = 0; i < 3; ++i) {
        bdt[i] = bv[i] * dt;
        dsv[i] = dv[i] * sdt;
#pragma unroll
        for (int j = 0; j < 3; ++j) {
            Adt[i][j] = A[i * 3 + j] * dt;
            Cs[i][j]  = C[i * 3 + j] * sdt;
        }
    }

    const float4 xb = *(const float4*)(trans + ((size_t)c * B_N + b) * 12);
    float x0r = xb.x, x1r = xb.y, x2r = xb.z;

    const float* __restrict__ nb = noise + (size_t)c * L * (B_N * 3) + (size_t)b * 3;
    const size_t nstride = (size_t)B_N * 3;

    float (*tile)[31] = lds[widx];

    // store roles: instr i writes paths {2i, 2i+1}; lanes 0-29 / 32-61 cover
    // 30 consecutive floats (120 B) of one path per instruction.
    const int  half = lane >> 5;              // 0 or 1
    const int  r    = lane & 31;              // 0..31
    const bool act  = r < 30;
    float* __restrict__ sb = out + (size_t)((pg << 6) + half) * ROWF
                                 + (size_t)(c * L + 1) * 3 + r;

    float bufA[FL][3], bufB[FL][3], bufC[FL][3];

    auto loadChunk = [&](float (&buf)[FL][3], int s) {
#pragma unroll
        for (int k = 0; k < FL; ++k) {
            const float* p = nb + ((size_t)s * FL + k) * nstride;
            buf[k][0] = p[0];
            buf[k][1] = p[1];
            buf[k][2] = p[2];
        }
    };

    auto doFlush = [&](const float (&buf)[FL][3], int fl) {
        float st[FL][3];
#pragma unroll
        for (int k = 0; k < FL; ++k) {
            const float e0 = buf[k][0], e1 = buf[k][1], e2 = buf[k][2];

            const float a0 = fmaf(Adt[0][2], x2r, fmaf(Adt[0][1], x1r, fmaf(Adt[0][0], x0r, bdt[0])));
            const float a1 = fmaf(Adt[1][2], x2r, fmaf(Adt[1][1], x1r, fmaf(Adt[1][0], x0r, bdt[1])));
            const float a2 = fmaf(Adt[2][2], x2r, fmaf(Adt[2][1], x1r, fmaf(Adt[2][0], x0r, bdt[2])));

            const float c0 = fmaf(Cs[0][2], x2r, fmaf(Cs[0][1], x1r, fmaf(Cs[0][0], x0r, dsv[0])));
            const float c1 = fmaf(Cs[1][2], x2r, fmaf(Cs[1][1], x1r, fmaf(Cs[1][0], x0r, dsv[1])));
            const float c2 = fmaf(Cs[2][2], x2r, fmaf(Cs[2][1], x1r, fmaf(Cs[2][0], x0r, dsv[2])));

            const float n0 = fmaf(c0, e0, x0r + a0);
            const float n1 = fmaf(c1, e1, x1r + a1);
            const float n2 = fmaf(c2, e2, x2r + a2);

            st[k][0] = n0; st[k][1] = n1; st[k][2] = n2;
            x0r = n0; x1r = n1; x2r = n2;
        }

        // WAR: previous flush's cross-lane LDS reads must be complete
        // (issued ~500 cycles ago -> near-zero actual wait)
        asm volatile("s_waitcnt lgkmcnt(0)" ::: "memory");

#pragma unroll
        for (int k = 0; k < FL; ++k) {
            tile[lane][k * 3 + 0] = st[k][0];
            tile[lane][k * 3 + 1] = st[k][1];
            tile[lane][k * 3 + 2] = st[k][2];
        }

        // RAW: writes visible before cross-lane reads
        asm volatile("s_waitcnt lgkmcnt(0)" ::: "memory");
        __builtin_amdgcn_sched_barrier(0);

        if (act) {
#pragma unroll
            for (int i = 0; i < 32; ++i) {
                const float val = tile[2 * i + half][r];
                sb[(size_t)(2 * i) * ROWF + fl * (FL * 3)] = val;
            }
        }
    };

    // Triple-buffered schedule: loads stay 2 flush-chunks ahead of compute.
    loadChunk(bufA, 0);
    loadChunk(bufB, 1);
    loadChunk(bufC, 2);
    doFlush(bufA, 0);
    loadChunk(bufA, 3);
    doFlush(bufB, 1);
    loadChunk(bufB, 4);
    doFlush(bufC, 2);
    doFlush(bufA, 3);
    doFlush(bufB, 4);
}

extern "C" void kernel_launch(void* const* d_in, const int* in_sizes, int n_in,
                              void* d_out, int out_size, void* d_ws, size_t ws_size,
                              hipStream_t stream) {
    const float* x0    = (const float*)d_in[0];
    const float* A     = (const float*)d_in[1];
    const float* bv    = (const float*)d_in[2];
    const float* C     = (const float*)d_in[3];
    const float* dv    = (const float*)d_in[4];
    const float* noise = (const float*)d_in[5];
    float* out = (float*)d_out;

    float* trans = (float*)d_ws;   // 9.83 MB

    dim3 gridPC(B_N / 64, NC);

    sde_chunk_transforms<<<gridPC, 64, 0, stream>>>(A, bv, C, dv, noise, trans);
    sde_scan<<<B_N / 64, 64, 0, stream>>>(x0, trans, out);
    sde_replay<<<(B_N / 64) * NC / 4, 256, 0, stream>>>(A, bv, C, dv, noise, trans, out);
}